// Round 14
// baseline (143.141 us; speedup 1.0000x reference)
//
#include <hip/hip_runtime.h>

typedef __bf16 bf16_t;
typedef __attribute__((ext_vector_type(8))) __bf16 bf16x8;
typedef __attribute__((ext_vector_type(4))) __bf16 bf16x4;
typedef __attribute__((ext_vector_type(2))) __bf16 bf16x2;
typedef __attribute__((ext_vector_type(4))) float f32x4;

#define S_LEN 4096
#define D_MODEL 1024
#define NH 16
#define DKH 64
#define WIN 256
#define NGLOB 16
#define HSZ (S_LEN * DKH)

// async 16B global->LDS copy (dest: wave-uniform base + lane*16)
__device__ inline void g2l16(const void* g, void* l) {
  __builtin_amdgcn_global_load_lds(
      (__attribute__((address_space(1))) void*)(void*)g,
      (__attribute__((address_space(3))) void*)l, 16, 0, 0);
}

// ---------------------------------------------------------------------------
// 256x256 counted-vmcnt pipelined GEMM for QKV (bf16 A,B^T; K=1024, BK=64).
// 8 waves (2M x 4N), per-wave 128x64 out = 8x4 frags of 16x16x32.
// LDS 128KB: As/Bs = [2 buf][2 half(128 rows)][128r][64c], row-XOR swizzle
// (slot t = s ^ (r&7); g2l16 dest linear, source pre-swizzled — rule 21;
// reads apply same XOR -> 2-way max, free).
// Pipeline (raw s_barrier, counted vmcnt — __syncthreads' vmcnt(0) is the
// stall, m233):
//   tile u: vmcnt(4 if A(u+1) in flight else 0); s_barrier;
//           issue B(u+1)->buf^1; ds_read A kk0+kk1 (16), B kk0 (4);
//           32 MFMA (kk0); lgkmcnt(0); s_barrier;   // A(u) region now free
//           issue A(u+2)->buf (overwrites A(u)); ds_read B kk1 (4);
//           32 MFMA (kk1).
// Hazards audited: A(u+2) lands only after block-wide A(u) read completion
// (lgkmcnt(0)+barrier); B(u+1) goes to the other buffer whose B-reads
// finished before this tile's top barrier; vmcnt(4) leaves only A(u+1).
// ---------------------------------------------------------------------------
__global__ __launch_bounds__(512, 2) void gemm_qkv(
    const bf16_t* __restrict__ Xq, const bf16_t* __restrict__ Xk,
    const bf16_t* __restrict__ Xv, const bf16_t* __restrict__ Wt,
    const float* __restrict__ bq, const float* __restrict__ bk,
    const float* __restrict__ bv, bf16_t* __restrict__ Qo,
    bf16_t* __restrict__ Ko, bf16_t* __restrict__ Vto) {
  __shared__ bf16_t As[2 * 2 * 128 * 64];  // 64KB
  __shared__ bf16_t Bs[2 * 2 * 128 * 64];  // 64KB

  const int lin = blockIdx.x;
  const int wg = ((lin & 7) * 24) + (lin >> 3);  // 192 = 8 XCD * 24, bijective
  const int which = wg >> 6;
  const int rem = wg & 63;
  const int n0 = (rem & 3) * 256;
  const int m0 = (rem >> 2) * 256;

  const bf16_t* A = which == 0 ? Xq : which == 1 ? Xk : Xv;
  const bf16_t* Bt = Wt + (size_t)which * (D_MODEL * D_MODEL);
  const float* bias = which == 0 ? bq : which == 1 ? bk : bv;

  const int tid = threadIdx.x;
  const int wid = tid >> 6, lane = tid & 63;
  const int wr = wid >> 2, wc = wid & 3;
  const int fr = lane & 15, fkg = lane >> 4;

  // staging: idx in 0..1023 covers one 128x64 half (16KB); 2 per thread.
  const int idx0 = tid, idx1 = 512 + tid;
  const int r0 = idx0 >> 3, sc0 = (((idx0 & 7) ^ (r0 & 7)) * 8);
  const int r1 = idx1 >> 3, sc1 = (((idx1 & 7) ^ (r1 & 7)) * 8);

#define STAGE_A(u, half)                                                      \
  {                                                                           \
    g2l16(A + (size_t)(m0 + (half)*128 + r0) * D_MODEL + (u)*64 + sc0,        \
          &As[((u)&1) * 16384 + (half)*8192 + idx0 * 8]);                     \
    g2l16(A + (size_t)(m0 + (half)*128 + r1) * D_MODEL + (u)*64 + sc1,        \
          &As[((u)&1) * 16384 + (half)*8192 + idx1 * 8]);                     \
  }
#define STAGE_B(u, half)                                                      \
  {                                                                           \
    g2l16(Bt + (size_t)(n0 + (half)*128 + r0) * D_MODEL + (u)*64 + sc0,       \
          &Bs[((u)&1) * 16384 + (half)*8192 + idx0 * 8]);                     \
    g2l16(Bt + (size_t)(n0 + (half)*128 + r1) * D_MODEL + (u)*64 + sc1,       \
          &Bs[((u)&1) * 16384 + (half)*8192 + idx1 * 8]);                     \
  }

  f32x4 acc[8][4];
#pragma unroll
  for (int i = 0; i < 8; i++)
#pragma unroll
    for (int j = 0; j < 4; j++) acc[i][j] = {0.f, 0.f, 0.f, 0.f};

  // prologue: A(0), B(0), A(1)  (12 vmcnt units; vmcnt(4) at u=0 leaves A(1))
  STAGE_A(0, 0) STAGE_A(0, 1) STAGE_B(0, 0) STAGE_B(0, 1)
  STAGE_A(1, 0) STAGE_A(1, 1)

  const int abase = wr * 8192;
  const int bbase = (wc >> 1) * 8192;

  for (int u = 0; u < 16; ++u) {
    const int bufo = (u & 1) * 16384;
    asm volatile("" ::: "memory");
    if (u < 15)
      asm volatile("s_waitcnt vmcnt(4)" ::: "memory");
    else
      asm volatile("s_waitcnt vmcnt(0)" ::: "memory");
    __builtin_amdgcn_s_barrier();
    asm volatile("" ::: "memory");
    if (u + 1 < 16) { STAGE_B(u + 1, 0) STAGE_B(u + 1, 1) }

    bf16x8 a0[8], a1[8], b0[4];
#pragma unroll
    for (int m = 0; m < 8; m++) {
      const int rh = m * 16 + fr;
      a0[m] = *(const bf16x8*)&As[bufo + abase + rh * 64 +
                                  ((fkg ^ (rh & 7)) * 8)];
      a1[m] = *(const bf16x8*)&As[bufo + abase + rh * 64 +
                                  (((4 + fkg) ^ (rh & 7)) * 8)];
    }
#pragma unroll
    for (int n = 0; n < 4; n++) {
      const int rh = (wc & 1) * 64 + n * 16 + fr;
      b0[n] = *(const bf16x8*)&Bs[bufo + bbase + rh * 64 +
                                  ((fkg ^ (rh & 7)) * 8)];
    }
    __builtin_amdgcn_s_setprio(1);
#pragma unroll
    for (int m = 0; m < 8; m++)
#pragma unroll
      for (int n = 0; n < 4; n++)
        acc[m][n] = __builtin_amdgcn_mfma_f32_16x16x32_bf16(a0[m], b0[n],
                                                            acc[m][n], 0, 0, 0);
    __builtin_amdgcn_s_setprio(0);

    asm volatile("s_waitcnt lgkmcnt(0)" ::: "memory");
    __builtin_amdgcn_s_barrier();
    asm volatile("" ::: "memory");
    if (u + 2 < 16) { STAGE_A(u + 2, 0) STAGE_A(u + 2, 1) }

    bf16x8 b1[4];
#pragma unroll
    for (int n = 0; n < 4; n++) {
      const int rh = (wc & 1) * 64 + n * 16 + fr;
      b1[n] = *(const bf16x8*)&Bs[bufo + bbase + rh * 64 +
                                  (((4 + fkg) ^ (rh & 7)) * 8)];
    }
    __builtin_amdgcn_s_setprio(1);
#pragma unroll
    for (int m = 0; m < 8; m++)
#pragma unroll
      for (int n = 0; n < 4; n++)
        acc[m][n] = __builtin_amdgcn_mfma_f32_16x16x32_bf16(a1[m], b1[n],
                                                            acc[m][n], 0, 0, 0);
    __builtin_amdgcn_s_setprio(0);
  }

  // epilogue
  const int cr = (lane >> 4) * 4;
  const int cc = lane & 15;
#pragma unroll
  for (int m = 0; m < 8; m++) {
    const int rowg = m0 + wr * 128 + m * 16 + cr;
#pragma unroll
    for (int n = 0; n < 4; n++) {
      const int colg = n0 + wc * 64 + n * 16 + cc;
      const float bv_ = bias[colg];
      const int h = colg >> 6, d = colg & 63;
#pragma unroll
      for (int r = 0; r < 4; r++) {
        const int s = rowg + r;
        const float v = acc[m][n][r] + bv_;
        if (which == 0)
          Qo[h * HSZ + s * DKH + d] = (bf16_t)(v * 0.125f);
        else if (which == 1)
          Ko[h * HSZ + s * DKH + d] = (bf16_t)v;
        else
          Vto[h * HSZ + d * S_LEN + s] = (bf16_t)v;
      }
    }
  }
#undef STAGE_A
#undef STAGE_B
}

// ---------------------------------------------------------------------------
// R6-verified 2-barrier GEMM body (bf16), for the output projection.
// ---------------------------------------------------------------------------
__device__ __forceinline__ void gemm_body(const bf16_t* __restrict__ Ah,
                                          const bf16_t* __restrict__ Bt,
                                          int m0, int n0, int wave, int lane,
                                          bf16_t* As, bf16_t* Bs,
                                          f32x4 acc[4][4]) {
  const int wr = wave >> 1, wc = wave & 1;
#pragma unroll
  for (int i = 0; i < 4; i++)
#pragma unroll
    for (int j = 0; j < 4; j++) acc[i][j] = {0.f, 0.f, 0.f, 0.f};

  const int ssl = (lane & 7) ^ (lane >> 3);
  const int srowB = 2 * (lane >> 3) + (ssl >> 2);
  const int scolB = 8 * (ssl & 3);
  const int fr = lane & 15;
  const int fkg = lane >> 4;

  for (int k0 = 0; k0 < D_MODEL; k0 += 32) {
#pragma unroll
    for (int i = 0; i < 2; i++) {
      const int c = wave * 2 + i;
      g2l16(Bt + (size_t)(n0 + c * 16 + srowB) * D_MODEL + k0 + scolB,
            &Bs[c * 512]);
      g2l16(Ah + (size_t)(m0 + c * 16 + srowB) * D_MODEL + k0 + scolB,
            &As[c * 512]);
    }
    __syncthreads();
    bf16x8 af[4], bfr[4];
#pragma unroll
    for (int m = 0; m < 4; m++) {
      const int rr = wr * 64 + m * 16 + fr;
      af[m] = *(const bf16x8*)&As[(rr >> 1) * 64 +
                                  ((((rr & 1) << 2) + fkg) ^ ((rr >> 1) & 7)) *
                                      8];
    }
#pragma unroll
    for (int n = 0; n < 4; n++) {
      const int rr = wc * 64 + n * 16 + fr;
      bfr[n] = *(const bf16x8*)&Bs[(rr >> 1) * 64 +
                                   ((((rr & 1) << 2) + fkg) ^ ((rr >> 1) & 7)) *
                                       8];
    }
#pragma unroll
    for (int m = 0; m < 4; m++)
#pragma unroll
      for (int n = 0; n < 4; n++)
        acc[m][n] = __builtin_amdgcn_mfma_f32_16x16x32_bf16(af[m], bfr[n],
                                                            acc[m][n], 0, 0, 0);
    __syncthreads();
  }
}

// Final output projection: f32 out with bias. 256 blocks, XCD-chunked.
__global__ __launch_bounds__(256) void gemm_out(const bf16_t* __restrict__ A_,
                                                const bf16_t* __restrict__ Bt_,
                                                const float* __restrict__ bias,
                                                float* __restrict__ Cout) {
  __shared__ bf16_t As[128 * 32];
  __shared__ bf16_t Bs[128 * 32];
  const int lin = blockIdx.x;
  const int wg = ((lin & 7) * 32) + (lin >> 3);  // 256 = 8 XCD * 32
  const int n0 = (wg & 7) * 128;
  const int m0 = (wg >> 3) * 128;
  const int wave = threadIdx.x >> 6, lane = threadIdx.x & 63;
  f32x4 acc[4][4];
  gemm_body(A_, Bt_, m0, n0, wave, lane, As, Bs, acc);

  const int wr = wave >> 1, wc = wave & 1;
  const int cr = (lane >> 4) * 4;
  const int cc = lane & 15;
#pragma unroll
  for (int m = 0; m < 4; m++) {
    const int rowg = m0 + wr * 64 + m * 16 + cr;
#pragma unroll
    for (int n = 0; n < 4; n++) {
      const int colg = n0 + wc * 64 + n * 16 + cc;
      const float bv_ = bias[colg];
#pragma unroll
      for (int r = 0; r < 4; r++)
        Cout[(size_t)(rowg + r) * D_MODEL + colg] = acc[m][n][r] + bv_;
    }
  }
}

// f32 -> bf16 for the 3 inputs in one launch (grid.x MUST be 4096).
__global__ void convx3(const float* __restrict__ q, const float* __restrict__ k,
                       const float* __restrict__ v, bf16_t* __restrict__ oq,
                       bf16_t* __restrict__ ok, bf16_t* __restrict__ ov) {
  const float* in = blockIdx.y == 0 ? q : blockIdx.y == 1 ? k : v;
  bf16_t* out = blockIdx.y == 0 ? oq : blockIdx.y == 1 ? ok : ov;
  const int i = (blockIdx.x * 256 + threadIdx.x) * 4;
  const float4 x = *(const float4*)&in[i];
  bf16x4 o = {(bf16_t)x.x, (bf16_t)x.y, (bf16_t)x.z, (bf16_t)x.w};
  *(bf16x4*)&out[i] = o;
}

// transpose+convert 4 weight matrices [K,N] f32 -> [N,K] bf16
__global__ void convw(const float* __restrict__ W0, const float* __restrict__ W1,
                      const float* __restrict__ W2, const float* __restrict__ W3,
                      bf16_t* __restrict__ out) {
  __shared__ float t[64][65];
  const float* W = blockIdx.z == 0 ? W0 : blockIdx.z == 1 ? W1
                  : blockIdx.z == 2 ? W2 : W3;
  bf16_t* Wt = out + (size_t)blockIdx.z * (D_MODEL * D_MODEL);
  const int k0 = blockIdx.y * 64, n0 = blockIdx.x * 64;
  const int tx = threadIdx.x & 63, ty = threadIdx.x >> 6;
#pragma unroll
  for (int i = 0; i < 16; i++) {
    const int r = i * 4 + ty;
    t[r][tx] = W[(size_t)(k0 + r) * D_MODEL + n0 + tx];
  }
  __syncthreads();
#pragma unroll
  for (int i = 0; i < 16; i++) {
    const int r = i * 4 + ty;
    Wt[(size_t)(n0 + r) * D_MODEL + k0 + tx] = (bf16_t)t[tx][r];
  }
}

// ---------------------------------------------------------------------------
// Sparse flash attention, swapped-QK^T, KVBLK=32 (R11-verified best).
// ---------------------------------------------------------------------------
__global__ __launch_bounds__(256) void attn_kern(const bf16_t* __restrict__ Q,
                                                 const bf16_t* __restrict__ K,
                                                 const bf16_t* __restrict__ V,
                                                 bf16_t* __restrict__ O) {
  __shared__ bf16_t p_lds[4][16 * 40];  // [wave][q*40 + k], padded
  const int wave = threadIdx.x >> 6, lane = threadIdx.x & 63;
  const int h = blockIdx.y;
  const int q0 = blockIdx.x * 64 + wave * 16;
  const bf16_t* Qh = Q + h * HSZ;
  const bf16_t* Kh = K + h * HSZ;
  const bf16_t* Vh = V + h * HSZ;  // V^T: [64][S]

  const int fr = lane & 15;
  const int fk = (lane >> 4) * 8;
  const int cr = (lane >> 4) * 4;

  const bf16x8 aq0 = *(const bf16x8*)&Qh[(q0 + fr) * DKH + fk];
  const bf16x8 aq1 = *(const bf16x8*)&Qh[(q0 + fr) * DKH + 32 + fk];

  f32x4 acc_o[4];
#pragma unroll
  for (int i = 0; i < 4; i++) acc_o[i] = {0.f, 0.f, 0.f, 0.f};
  float m_run = -1e30f, l_run = 0.f;

  const int kt_end = (q0 + 15) >> 5;
  int kt_lo = (q0 - WIN) >> 5;
  if (kt_lo < 0) kt_lo = 0;
  const int nt = kt_end - kt_lo + 1 + (kt_lo > 0 ? 1 : 0);

#define TILE_KB(t) ((kt_lo > 0) ? ((t) == 0 ? 0 : (kt_lo + (t)-1) * 32) : (t)*32)
#define LOADK(kb, A0, A1, A2, A3)                              \
  A0 = *(const bf16x8*)&Kh[((kb) + fr) * DKH + fk];            \
  A1 = *(const bf16x8*)&Kh[((kb) + fr) * DKH + 32 + fk];       \
  A2 = *(const bf16x8*)&Kh[((kb) + 16 + fr) * DKH + fk];       \
  A3 = *(const bf16x8*)&Kh[((kb) + 16 + fr) * DKH + 32 + fk];

  bf16x8 kc0, kc1, kc2, kc3;
  {
    const int kb0 = TILE_KB(0);
    LOADK(kb0, kc0, kc1, kc2, kc3)
  }

  const int iq = q0 + fr;
  bf16_t* prow = &p_lds[wave][fr * 40];
  const bf16x8* pread = (const bf16x8*)&p_lds[wave][fr * 40 + fk];

  for (int t = 0; t < nt; t++) {
    const int kb = TILE_KB(t);
    bf16x8 kn0, kn1, kn2, kn3;
    const bool have_next = (t + 1 < nt);
    if (have_next) {
      const int nkb = TILE_KB(t + 1);
      LOADK(nkb, kn0, kn1, kn2, kn3)
    }
    bf16x8 vf0 = *(const bf16x8*)&Vh[(0 * 16 + fr) * S_LEN + kb + fk];
    bf16x8 vf1 = *(const bf16x8*)&Vh[(1 * 16 + fr) * S_LEN + kb + fk];
    bf16x8 vf2 = *(const bf16x8*)&Vh[(2 * 16 + fr) * S_LEN + kb + fk];
    bf16x8 vf3 = *(const bf16x8*)&Vh[(3 * 16 + fr) * S_LEN + kb + fk];

    f32x4 s0 = {0.f, 0.f, 0.f, 0.f}, s1 = {0.f, 0.f, 0.f, 0.f};
    s0 = __builtin_amdgcn_mfma_f32_16x16x32_bf16(kc0, aq0, s0, 0, 0, 0);
    s0 = __builtin_amdgcn_mfma_f32_16x16x32_bf16(kc1, aq1, s0, 0, 0, 0);
    s1 = __builtin_amdgcn_mfma_f32_16x16x32_bf16(kc2, aq0, s1, 0, 0, 0);
    s1 = __builtin_amdgcn_mfma_f32_16x16x32_bf16(kc3, aq1, s1, 0, 0, 0);

    float v[8];
#pragma unroll
    for (int r = 0; r < 4; r++) {
      const int j0 = kb + cr + r, j1 = j0 + 16;
      v[r] = (j0 <= iq && (iq - j0 <= WIN || j0 < NGLOB)) ? s0[r] : -1e30f;
      v[4 + r] = (j1 <= iq && (iq - j1 <= WIN || j1 < NGLOB)) ? s1[r] : -1e30f;
    }
    float mt = fmaxf(fmaxf(fmaxf(v[0], v[1]), fmaxf(v[2], v[3])),
                     fmaxf(fmaxf(v[4], v[5]), fmaxf(v[6], v[7])));
    mt = fmaxf(mt, __shfl_xor(mt, 16));
    mt = fmaxf(mt, __shfl_xor(mt, 32));
    const float mn = fmaxf(m_run, mt);
    const float alpha = __expf(m_run - mn);
    m_run = mn;
    float p[8];
    float ps = 0.f;
#pragma unroll
    for (int i = 0; i < 8; i++) {
      p[i] = __expf(v[i] - mn);
      ps += p[i];
    }
    ps += __shfl_xor(ps, 16);
    ps += __shfl_xor(ps, 32);
    l_run = l_run * alpha + ps;

    *(bf16x2*)&prow[cr] = bf16x2{(bf16_t)p[0], (bf16_t)p[1]};
    *(bf16x2*)&prow[cr + 2] = bf16x2{(bf16_t)p[2], (bf16_t)p[3]};
    *(bf16x2*)&prow[16 + cr] = bf16x2{(bf16_t)p[4], (bf16_t)p[5]};
    *(bf16x2*)&prow[16 + cr + 2] = bf16x2{(bf16_t)p[6], (bf16_t)p[7]};

    float alpha_r[4];
#pragma unroll
    for (int r = 0; r < 4; r++) alpha_r[r] = __shfl(alpha, cr + r);

    asm volatile("" ::: "memory");
    const bf16x8 pa = *pread;
    asm volatile("" ::: "memory");

#pragma unroll
    for (int fd = 0; fd < 4; fd++) {
#pragma unroll
      for (int r = 0; r < 4; r++) acc_o[fd][r] *= alpha_r[r];
    }
    acc_o[0] = __builtin_amdgcn_mfma_f32_16x16x32_bf16(pa, vf0, acc_o[0], 0, 0, 0);
    acc_o[1] = __builtin_amdgcn_mfma_f32_16x16x32_bf16(pa, vf1, acc_o[1], 0, 0, 0);
    acc_o[2] = __builtin_amdgcn_mfma_f32_16x16x32_bf16(pa, vf2, acc_o[2], 0, 0, 0);
    acc_o[3] = __builtin_amdgcn_mfma_f32_16x16x32_bf16(pa, vf3, acc_o[3], 0, 0, 0);

    if (have_next) {
      kc0 = kn0; kc1 = kn1; kc2 = kn2; kc3 = kn3;
    }
  }

  const float linv = 1.0f / l_run;
  float inv_r[4];
#pragma unroll
  for (int r = 0; r < 4; r++) inv_r[r] = __shfl(linv, cr + r);

#pragma unroll
  for (int fd = 0; fd < 4; fd++)
#pragma unroll
    for (int r = 0; r < 4; r++) {
      const int s = q0 + cr + r;
      O[(size_t)s * D_MODEL + h * DKH + fd * 16 + fr] =
          (bf16_t)(acc_o[fd][r] * inv_r[r]);
    }
}

extern "C" void kernel_launch(void* const* d_in, const int* in_sizes, int n_in,
                              void* d_out, int out_size, void* d_ws,
                              size_t ws_size, hipStream_t stream) {
  const float* query = (const float*)d_in[0];
  const float* key = (const float*)d_in[1];
  const float* value = (const float*)d_in[2];
  const float* Wq = (const float*)d_in[3];
  const float* bq = (const float*)d_in[4];
  const float* Wk = (const float*)d_in[5];
  const float* bk = (const float*)d_in[6];
  const float* Wv = (const float*)d_in[7];
  const float* bv = (const float*)d_in[8];
  const float* Wo = (const float*)d_in[9];
  const float* bo = (const float*)d_in[10];

  char* ws = (char*)d_ws;
  bf16_t* Qb = (bf16_t*)(ws);                   // 8 MiB [16][4096][64]
  bf16_t* Kb = (bf16_t*)(ws + (8ull << 20));    // 8 MiB
  bf16_t* Vtb = (bf16_t*)(ws + (16ull << 20));  // 8 MiB [16][64][4096]
  bf16_t* Wt = (bf16_t*)(ws + (24ull << 20));   // 4 x 2 MiB (Wq^T..Wo^T)
  bf16_t* Xq = (bf16_t*)(ws + (32ull << 20));   // 8 MiB
  bf16_t* Xk = (bf16_t*)(ws + (40ull << 20));   // 8 MiB
  bf16_t* Xv = (bf16_t*)(ws + (48ull << 20));   // 8 MiB
  bf16_t* Ab = (bf16_t*)(ws + (56ull << 20));   // 8 MiB attn out [4096][1024]

  const size_t WSTRIDE = (size_t)D_MODEL * D_MODEL;

  convw<<<dim3(16, 16, 4), 256, 0, stream>>>(Wq, Wk, Wv, Wo, Wt);
  convx3<<<dim3(4096, 3), 256, 0, stream>>>(query, key, value, Xq, Xk, Xv);

  gemm_qkv<<<192, 512, 0, stream>>>(Xq, Xk, Xv, Wt, bq, bk, bv, Qb, Kb, Vtb);

  attn_kern<<<dim3(64, 16), 256, 0, stream>>>(Qb, Kb, Vtb, Ab);

  gemm_out<<<256, 256, 0, stream>>>(Ab, Wt + 3 * WSTRIDE, bo, (float*)d_out);
}

// Round 15
// 132.166 us; speedup vs baseline: 1.0830x; 1.0830x over previous
//
#include <hip/hip_runtime.h>

typedef __bf16 bf16_t;
typedef __attribute__((ext_vector_type(8))) __bf16 bf16x8;
typedef __attribute__((ext_vector_type(4))) __bf16 bf16x4;
typedef __attribute__((ext_vector_type(2))) __bf16 bf16x2;
typedef __attribute__((ext_vector_type(4))) float f32x4;

#define S_LEN 4096
#define D_MODEL 1024
#define NH 16
#define DKH 64
#define WIN 256
#define NGLOB 16
#define HSZ (S_LEN * DKH)

// async 16B global->LDS copy (dest: wave-uniform base + lane*16)
__device__ inline void g2l16(const void* g, void* l) {
  __builtin_amdgcn_global_load_lds(
      (__attribute__((address_space(1))) void*)(void*)g,
      (__attribute__((address_space(3))) void*)l, 16, 0, 0);
}

// ---------------------------------------------------------------------------
// R6-verified 2-barrier GEMM body (bf16 A,B^T): fastest measured structure
// for this shape (57.8us qkv, 0 bank conflicts, ~ideal fetch).
// 128x128 tile, BK=32, 4 waves (2x2), 4x4 frags of 16x16x32, 16KB LDS.
// Row-pair XOR swizzle, source-side for g2l16 (rule 21), same XOR on reads.
// ---------------------------------------------------------------------------
__device__ __forceinline__ void gemm_body(const bf16_t* __restrict__ Ah,
                                          const bf16_t* __restrict__ Bt,
                                          int m0, int n0, int wave, int lane,
                                          bf16_t* As, bf16_t* Bs,
                                          f32x4 acc[4][4]) {
  const int wr = wave >> 1, wc = wave & 1;
#pragma unroll
  for (int i = 0; i < 4; i++)
#pragma unroll
    for (int j = 0; j < 4; j++) acc[i][j] = {0.f, 0.f, 0.f, 0.f};

  const int ssl = (lane & 7) ^ (lane >> 3);
  const int srowB = 2 * (lane >> 3) + (ssl >> 2);
  const int scolB = 8 * (ssl & 3);
  const int fr = lane & 15;
  const int fkg = lane >> 4;

  for (int k0 = 0; k0 < D_MODEL; k0 += 32) {
#pragma unroll
    for (int i = 0; i < 2; i++) {
      const int c = wave * 2 + i;
      g2l16(Bt + (size_t)(n0 + c * 16 + srowB) * D_MODEL + k0 + scolB,
            &Bs[c * 512]);
      g2l16(Ah + (size_t)(m0 + c * 16 + srowB) * D_MODEL + k0 + scolB,
            &As[c * 512]);
    }
    __syncthreads();
    bf16x8 af[4], bfr[4];
#pragma unroll
    for (int m = 0; m < 4; m++) {
      const int rr = wr * 64 + m * 16 + fr;
      af[m] = *(const bf16x8*)&As[(rr >> 1) * 64 +
                                  ((((rr & 1) << 2) + fkg) ^ ((rr >> 1) & 7)) *
                                      8];
    }
#pragma unroll
    for (int n = 0; n < 4; n++) {
      const int rr = wc * 64 + n * 16 + fr;
      bfr[n] = *(const bf16x8*)&Bs[(rr >> 1) * 64 +
                                   ((((rr & 1) << 2) + fkg) ^ ((rr >> 1) & 7)) *
                                       8];
    }
#pragma unroll
    for (int m = 0; m < 4; m++)
#pragma unroll
      for (int n = 0; n < 4; n++)
        acc[m][n] = __builtin_amdgcn_mfma_f32_16x16x32_bf16(af[m], bfr[n],
                                                            acc[m][n], 0, 0, 0);
    __syncthreads();
  }
}

// ---------------------------------------------------------------------------
// Fused Q/K/V projection (bf16 inputs from conv_all). 768 blocks, XCD-chunked
// (96/XCD, n-fastest) so the 8 n-blocks sharing an A-panel share an L2.
// which=0: Q bf16 [h][s][64] scaled 0.125; 1: K bf16; 2: V^T bf16 [h][64][s].
// ---------------------------------------------------------------------------
__global__ __launch_bounds__(256) void gemm_qkv(
    const bf16_t* __restrict__ Xq, const bf16_t* __restrict__ Xk,
    const bf16_t* __restrict__ Xv, const bf16_t* __restrict__ Wt,
    const float* __restrict__ bq, const float* __restrict__ bk,
    const float* __restrict__ bv, bf16_t* __restrict__ Qo,
    bf16_t* __restrict__ Ko, bf16_t* __restrict__ Vto) {
  __shared__ bf16_t As[128 * 32];
  __shared__ bf16_t Bs[128 * 32];
  const int lin = blockIdx.x;
  const int wg = ((lin & 7) * 96) + (lin >> 3);  // 768 = 8 XCD * 96
  const int n0 = (wg & 7) * 128;
  const int m0 = ((wg >> 3) & 31) * 128;
  const int which = wg >> 8;

  const bf16_t* A = which == 0 ? Xq : which == 1 ? Xk : Xv;
  const bf16_t* Bt = Wt + (size_t)which * (D_MODEL * D_MODEL);
  const float* bias = which == 0 ? bq : which == 1 ? bk : bv;

  const int wave = threadIdx.x >> 6, lane = threadIdx.x & 63;
  f32x4 acc[4][4];
  gemm_body(A, Bt, m0, n0, wave, lane, As, Bs, acc);

  const int wr = wave >> 1, wc = wave & 1;
  const int cr = (lane >> 4) * 4;
  const int cc = lane & 15;
#pragma unroll
  for (int m = 0; m < 4; m++) {
    const int rowg = m0 + wr * 64 + m * 16 + cr;
#pragma unroll
    for (int n = 0; n < 4; n++) {
      const int colg = n0 + wc * 64 + n * 16 + cc;
      const float bv_ = bias[colg];
      const int h = colg >> 6, d = colg & 63;
#pragma unroll
      for (int r = 0; r < 4; r++) {
        const int s = rowg + r;
        const float v = acc[m][n][r] + bv_;
        if (which == 0)
          Qo[h * HSZ + s * DKH + d] = (bf16_t)(v * 0.125f);
        else if (which == 1)
          Ko[h * HSZ + s * DKH + d] = (bf16_t)v;
        else
          Vto[h * HSZ + d * S_LEN + s] = (bf16_t)v;
      }
    }
  }
}

// Final output projection: f32 out with bias. 256 blocks, XCD-chunked.
__global__ __launch_bounds__(256) void gemm_out(const bf16_t* __restrict__ A_,
                                                const bf16_t* __restrict__ Bt_,
                                                const float* __restrict__ bias,
                                                float* __restrict__ Cout) {
  __shared__ bf16_t As[128 * 32];
  __shared__ bf16_t Bs[128 * 32];
  const int lin = blockIdx.x;
  const int wg = ((lin & 7) * 32) + (lin >> 3);  // 256 = 8 XCD * 32
  const int n0 = (wg & 7) * 128;
  const int m0 = (wg >> 3) * 128;
  const int wave = threadIdx.x >> 6, lane = threadIdx.x & 63;
  f32x4 acc[4][4];
  gemm_body(A_, Bt_, m0, n0, wave, lane, As, Bs, acc);

  const int wr = wave >> 1, wc = wave & 1;
  const int cr = (lane >> 4) * 4;
  const int cc = lane & 15;
#pragma unroll
  for (int m = 0; m < 4; m++) {
    const int rowg = m0 + wr * 64 + m * 16 + cr;
#pragma unroll
    for (int n = 0; n < 4; n++) {
      const int colg = n0 + wc * 64 + n * 16 + cc;
      const float bv_ = bias[colg];
#pragma unroll
      for (int r = 0; r < 4; r++)
        Cout[(size_t)(rowg + r) * D_MODEL + colg] = acc[m][n][r] + bv_;
    }
  }
}

// ---------------------------------------------------------------------------
// All conversions in ONE launch (saves a kernel + gap):
//   bid < 12288: f32->bf16 input convert (which = bid>>12; 4096 blocks each)
//   bid >= 12288: weight transpose+convert [K,N] f32 -> [N,K] bf16
//                 (4 matrices x 256 blocks of 64x64 tiles)
// ---------------------------------------------------------------------------
__global__ __launch_bounds__(256) void conv_all(
    const float* __restrict__ q, const float* __restrict__ k,
    const float* __restrict__ v, const float* __restrict__ W0,
    const float* __restrict__ W1, const float* __restrict__ W2,
    const float* __restrict__ W3, bf16_t* __restrict__ oq,
    bf16_t* __restrict__ ok, bf16_t* __restrict__ ov,
    bf16_t* __restrict__ Wt) {
  __shared__ float t[64][65];
  const int bid = blockIdx.x;
  if (bid < 12288) {
    const int which = bid >> 12;
    const int blk = bid & 4095;
    const float* in = which == 0 ? q : which == 1 ? k : v;
    bf16_t* out = which == 0 ? oq : which == 1 ? ok : ov;
    const int i = (blk * 256 + threadIdx.x) * 4;
    const float4 x = *(const float4*)&in[i];
    bf16x4 o = {(bf16_t)x.x, (bf16_t)x.y, (bf16_t)x.z, (bf16_t)x.w};
    *(bf16x4*)&out[i] = o;
  } else {
    const int wb = bid - 12288;  // 0..1023
    const int wz = wb >> 8;      // matrix 0..3
    const int rem = wb & 255;
    const float* W = wz == 0 ? W0 : wz == 1 ? W1 : wz == 2 ? W2 : W3;
    bf16_t* Wo = Wt + (size_t)wz * (D_MODEL * D_MODEL);
    const int k0 = (rem >> 4) * 64, n0 = (rem & 15) * 64;
    const int tx = threadIdx.x & 63, ty = threadIdx.x >> 6;
#pragma unroll
    for (int i = 0; i < 16; i++) {
      const int r = i * 4 + ty;
      t[r][tx] = W[(size_t)(k0 + r) * D_MODEL + n0 + tx];
    }
    __syncthreads();
#pragma unroll
    for (int i = 0; i < 16; i++) {
      const int r = i * 4 + ty;
      Wo[(size_t)(n0 + r) * D_MODEL + k0 + tx] = (bf16_t)t[tx][r];
    }
  }
}

// ---------------------------------------------------------------------------
// Sparse flash attention, swapped-QK^T, KVBLK=32 (R11-verified best), with
// XCD-chunked block swizzle: 1024 blocks -> each XCD serves 2 heads, so a
// head's K/V (~1MB) stays in its 4MB L2 (T1 mechanism: inter-block reuse).
// ---------------------------------------------------------------------------
__global__ __launch_bounds__(256) void attn_kern(const bf16_t* __restrict__ Q,
                                                 const bf16_t* __restrict__ K,
                                                 const bf16_t* __restrict__ V,
                                                 bf16_t* __restrict__ O) {
  __shared__ bf16_t p_lds[4][16 * 40];  // [wave][q*40 + k], padded
  const int wave = threadIdx.x >> 6, lane = threadIdx.x & 63;
  const int lin = blockIdx.x;
  const int wg = (lin & 7) * 128 + (lin >> 3);  // 1024 = 8 XCD * 128
  const int h = wg >> 6;
  const int q0 = (wg & 63) * 64 + wave * 16;
  const bf16_t* Qh = Q + h * HSZ;
  const bf16_t* Kh = K + h * HSZ;
  const bf16_t* Vh = V + h * HSZ;  // V^T: [64][S]

  const int fr = lane & 15;
  const int fk = (lane >> 4) * 8;
  const int cr = (lane >> 4) * 4;

  const bf16x8 aq0 = *(const bf16x8*)&Qh[(q0 + fr) * DKH + fk];
  const bf16x8 aq1 = *(const bf16x8*)&Qh[(q0 + fr) * DKH + 32 + fk];

  f32x4 acc_o[4];
#pragma unroll
  for (int i = 0; i < 4; i++) acc_o[i] = {0.f, 0.f, 0.f, 0.f};
  float m_run = -1e30f, l_run = 0.f;

  const int kt_end = (q0 + 15) >> 5;
  int kt_lo = (q0 - WIN) >> 5;
  if (kt_lo < 0) kt_lo = 0;
  const int nt = kt_end - kt_lo + 1 + (kt_lo > 0 ? 1 : 0);

#define TILE_KB(t) ((kt_lo > 0) ? ((t) == 0 ? 0 : (kt_lo + (t)-1) * 32) : (t)*32)
#define LOADK(kb, A0, A1, A2, A3)                              \
  A0 = *(const bf16x8*)&Kh[((kb) + fr) * DKH + fk];            \
  A1 = *(const bf16x8*)&Kh[((kb) + fr) * DKH + 32 + fk];       \
  A2 = *(const bf16x8*)&Kh[((kb) + 16 + fr) * DKH + fk];       \
  A3 = *(const bf16x8*)&Kh[((kb) + 16 + fr) * DKH + 32 + fk];

  bf16x8 kc0, kc1, kc2, kc3;
  {
    const int kb0 = TILE_KB(0);
    LOADK(kb0, kc0, kc1, kc2, kc3)
  }

  const int iq = q0 + fr;
  bf16_t* prow = &p_lds[wave][fr * 40];
  const bf16x8* pread = (const bf16x8*)&p_lds[wave][fr * 40 + fk];

  for (int t = 0; t < nt; t++) {
    const int kb = TILE_KB(t);
    bf16x8 kn0, kn1, kn2, kn3;
    const bool have_next = (t + 1 < nt);
    if (have_next) {
      const int nkb = TILE_KB(t + 1);
      LOADK(nkb, kn0, kn1, kn2, kn3)
    }
    bf16x8 vf0 = *(const bf16x8*)&Vh[(0 * 16 + fr) * S_LEN + kb + fk];
    bf16x8 vf1 = *(const bf16x8*)&Vh[(1 * 16 + fr) * S_LEN + kb + fk];
    bf16x8 vf2 = *(const bf16x8*)&Vh[(2 * 16 + fr) * S_LEN + kb + fk];
    bf16x8 vf3 = *(const bf16x8*)&Vh[(3 * 16 + fr) * S_LEN + kb + fk];

    f32x4 s0 = {0.f, 0.f, 0.f, 0.f}, s1 = {0.f, 0.f, 0.f, 0.f};
    s0 = __builtin_amdgcn_mfma_f32_16x16x32_bf16(kc0, aq0, s0, 0, 0, 0);
    s0 = __builtin_amdgcn_mfma_f32_16x16x32_bf16(kc1, aq1, s0, 0, 0, 0);
    s1 = __builtin_amdgcn_mfma_f32_16x16x32_bf16(kc2, aq0, s1, 0, 0, 0);
    s1 = __builtin_amdgcn_mfma_f32_16x16x32_bf16(kc3, aq1, s1, 0, 0, 0);

    float v[8];
#pragma unroll
    for (int r = 0; r < 4; r++) {
      const int j0 = kb + cr + r, j1 = j0 + 16;
      v[r] = (j0 <= iq && (iq - j0 <= WIN || j0 < NGLOB)) ? s0[r] : -1e30f;
      v[4 + r] = (j1 <= iq && (iq - j1 <= WIN || j1 < NGLOB)) ? s1[r] : -1e30f;
    }
    float mt = fmaxf(fmaxf(fmaxf(v[0], v[1]), fmaxf(v[2], v[3])),
                     fmaxf(fmaxf(v[4], v[5]), fmaxf(v[6], v[7])));
    mt = fmaxf(mt, __shfl_xor(mt, 16));
    mt = fmaxf(mt, __shfl_xor(mt, 32));
    const float mn = fmaxf(m_run, mt);
    const float alpha = __expf(m_run - mn);
    m_run = mn;
    float p[8];
    float ps = 0.f;
#pragma unroll
    for (int i = 0; i < 8; i++) {
      p[i] = __expf(v[i] - mn);
      ps += p[i];
    }
    ps += __shfl_xor(ps, 16);
    ps += __shfl_xor(ps, 32);
    l_run = l_run * alpha + ps;

    *(bf16x2*)&prow[cr] = bf16x2{(bf16_t)p[0], (bf16_t)p[1]};
    *(bf16x2*)&prow[cr + 2] = bf16x2{(bf16_t)p[2], (bf16_t)p[3]};
    *(bf16x2*)&prow[16 + cr] = bf16x2{(bf16_t)p[4], (bf16_t)p[5]};
    *(bf16x2*)&prow[16 + cr + 2] = bf16x2{(bf16_t)p[6], (bf16_t)p[7]};

    float alpha_r[4];
#pragma unroll
    for (int r = 0; r < 4; r++) alpha_r[r] = __shfl(alpha, cr + r);

    asm volatile("" ::: "memory");
    const bf16x8 pa = *pread;
    asm volatile("" ::: "memory");

#pragma unroll
    for (int fd = 0; fd < 4; fd++) {
#pragma unroll
      for (int r = 0; r < 4; r++) acc_o[fd][r] *= alpha_r[r];
    }
    acc_o[0] = __builtin_amdgcn_mfma_f32_16x16x32_bf16(pa, vf0, acc_o[0], 0, 0, 0);
    acc_o[1] = __builtin_amdgcn_mfma_f32_16x16x32_bf16(pa, vf1, acc_o[1], 0, 0, 0);
    acc_o[2] = __builtin_amdgcn_mfma_f32_16x16x32_bf16(pa, vf2, acc_o[2], 0, 0, 0);
    acc_o[3] = __builtin_amdgcn_mfma_f32_16x16x32_bf16(pa, vf3, acc_o[3], 0, 0, 0);

    if (have_next) {
      kc0 = kn0; kc1 = kn1; kc2 = kn2; kc3 = kn3;
    }
  }

  const float linv = 1.0f / l_run;
  float inv_r[4];
#pragma unroll
  for (int r = 0; r < 4; r++) inv_r[r] = __shfl(linv, cr + r);

#pragma unroll
  for (int fd = 0; fd < 4; fd++)
#pragma unroll
    for (int r = 0; r < 4; r++) {
      const int s = q0 + cr + r;
      O[(size_t)s * D_MODEL + h * DKH + fd * 16 + fr] =
          (bf16_t)(acc_o[fd][r] * inv_r[r]);
    }
}

extern "C" void kernel_launch(void* const* d_in, const int* in_sizes, int n_in,
                              void* d_out, int out_size, void* d_ws,
                              size_t ws_size, hipStream_t stream) {
  const float* query = (const float*)d_in[0];
  const float* key = (const float*)d_in[1];
  const float* value = (const float*)d_in[2];
  const float* Wq = (const float*)d_in[3];
  const float* bq = (const float*)d_in[4];
  const float* Wk = (const float*)d_in[5];
  const float* bk = (const float*)d_in[6];
  const float* Wv = (const float*)d_in[7];
  const float* bv = (const float*)d_in[8];
  const float* Wo = (const float*)d_in[9];
  const float* bo = (const float*)d_in[10];

  char* ws = (char*)d_ws;
  bf16_t* Qb = (bf16_t*)(ws);                   // 8 MiB [16][4096][64]
  bf16_t* Kb = (bf16_t*)(ws + (8ull << 20));    // 8 MiB
  bf16_t* Vtb = (bf16_t*)(ws + (16ull << 20));  // 8 MiB [16][64][4096]
  bf16_t* Wt = (bf16_t*)(ws + (24ull << 20));   // 4 x 2 MiB (Wq^T..Wo^T)
  bf16_t* Xq = (bf16_t*)(ws + (32ull << 20));   // 8 MiB
  bf16_t* Xk = (bf16_t*)(ws + (40ull << 20));   // 8 MiB
  bf16_t* Xv = (bf16_t*)(ws + (48ull << 20));   // 8 MiB
  bf16_t* Ab = (bf16_t*)(ws + (56ull << 20));   // 8 MiB attn out [4096][1024]

  const size_t WSTRIDE = (size_t)D_MODEL * D_MODEL;

  conv_all<<<13312, 256, 0, stream>>>(query, key, value, Wq, Wk, Wv, Wo, Xq,
                                      Xk, Xv, Wt);

  gemm_qkv<<<768, 256, 0, stream>>>(Xq, Xk, Xv, Wt, bq, bk, bv, Qb, Kb, Vtb);

  attn_kern<<<1024, 256, 0, stream>>>(Qb, Kb, Vtb, Ab);

  gemm_out<<<256, 256, 0, stream>>>(Ab, Wt + 3 * WSTRIDE, bo, (float*)d_out);
}